// Round 5
// baseline (388.449 us; speedup 1.0000x reference)
//
#include <hip/hip_runtime.h>
#include <hip/hip_bf16.h>

#define BB 2
#define SS 4096
#define CC 512
#define HH 8
#define DD 64
#define MM (BB*SS)

typedef __bf16 bf16;
typedef __attribute__((ext_vector_type(8))) __bf16 bf16x8;
typedef __attribute__((ext_vector_type(4))) __bf16 bf16x4;
typedef __attribute__((ext_vector_type(4))) float f32x4;

#define LP 72  // LDS row stride (64 + 8 pad), multiple of 8 -> 16B-aligned rows
#define QSCALE 0.18033688f  // 1/sqrt(64) * log2(e), folded into Wq at cvt time

__device__ __forceinline__ bf16x8 cvt8(const float4 a, const float4 b) {
  bf16x8 r;
  r[0]=(bf16)a.x; r[1]=(bf16)a.y; r[2]=(bf16)a.z; r[3]=(bf16)a.w;
  r[4]=(bf16)b.x; r[5]=(bf16)b.y; r[6]=(bf16)b.z; r[7]=(bf16)b.w;
  return r;
}

__device__ __forceinline__ bf16x8 vcat(bf16x4 lo, bf16x4 hi) {
  bf16x8 r;
  r[0]=lo[0]; r[1]=lo[1]; r[2]=lo[2]; r[3]=lo[3];
  r[4]=hi[0]; r[5]=hi[1]; r[6]=hi[2]; r[7]=hi[3];
  return r;
}

// ---------------------------------------------------------------------------
// Kernel 0: elementwise fp32 -> bf16 (X, Wo).
// ---------------------------------------------------------------------------
__global__ __launch_bounds__(256) void cvt_f32_bf16(
    const float* __restrict__ src, bf16* __restrict__ dst)
{
  size_t e = ((size_t)blockIdx.x * 256 + threadIdx.x) * 8;
  float4 a = ((const float4*)(src + e))[0];
  float4 b = ((const float4*)(src + e))[1];
  *(bf16x8*)(dst + e) = cvt8(a, b);
}

// ---------------------------------------------------------------------------
// Kernel 0b: fused Wq|Wk|Wv -> bf16 [1536][512], QSCALE folded into Wq.
// ---------------------------------------------------------------------------
__global__ __launch_bounds__(256) void cvt_w(
    const float* __restrict__ Wq, const float* __restrict__ Wk,
    const float* __restrict__ Wv, bf16* __restrict__ Wb)
{
  size_t e = ((size_t)blockIdx.x * 256 + threadIdx.x) * 8;  // < 786432
  const int tens = (int)(e >> 18);                          // 262144 per W
  const float* src = ((tens == 0) ? Wq : (tens == 1) ? Wk : Wv) + (e & 262143);
  const float sc = (tens == 0) ? QSCALE : 1.f;
  float4 a = ((const float4*)src)[0];
  float4 b = ((const float4*)src)[1];
  bf16x8 r;
  r[0]=(bf16)(a.x*sc); r[1]=(bf16)(a.y*sc); r[2]=(bf16)(a.z*sc); r[3]=(bf16)(a.w*sc);
  r[4]=(bf16)(b.x*sc); r[5]=(bf16)(b.y*sc); r[6]=(bf16)(b.z*sc); r[7]=(bf16)(b.w*sc);
  *(bf16x8*)(Wb + e) = r;
}

// ---------------------------------------------------------------------------
// Kernel 1: fused QKV projection — VERBATIM R10 green (2x2 mosaic, bf16).
// ---------------------------------------------------------------------------
__global__ __launch_bounds__(256) void qkv_gemm(
    const bf16* __restrict__ Xb, const bf16* __restrict__ Wb,
    bf16* __restrict__ qp, bf16* __restrict__ kp, bf16* __restrict__ vtp)
{
  __shared__ bf16 Aa[64*LP];
  __shared__ bf16 Ab[64*LP];
  __shared__ bf16 Ba[64*LP];
  __shared__ bf16 Bb[64*LP];
  const int m0  = blockIdx.x * 128;        // m-pair: m0, m0+64
  const int nf0 = blockIdx.y * 128;        // n-pair within fused [0,1536)
  const int tens = nf0 >> 9;               // 128 divides 512 -> uniform
  const int n0 = nf0 & 511;                // first n-strip; second is n0+64

  const int t = threadIdx.x;
  const int w = t >> 6;
  const int lane = t & 63;
  const int l15 = lane & 15;
  const int quad = lane >> 4;
  const int srow = t >> 2;
  const int scol = (t & 3) << 4;

  f32x4 acc[2][2][4];  // [mi][ni][nt]
  #pragma unroll
  for (int mi = 0; mi < 2; ++mi)
    #pragma unroll
    for (int ni = 0; ni < 2; ++ni)
      #pragma unroll
      for (int nt = 0; nt < 4; ++nt)
        #pragma unroll
        for (int r = 0; r < 4; ++r) acc[mi][ni][nt][r] = 0.f;

  for (int k0 = 0; k0 < CC; k0 += 64) {
    __syncthreads();
    {
      const bf16* sa = Xb + (size_t)(m0 + srow) * CC + k0 + scol;
      *(bf16x8*)&Aa[srow*LP + scol]     = ((const bf16x8*)sa)[0];
      *(bf16x8*)&Aa[srow*LP + scol + 8] = ((const bf16x8*)sa)[1];
      const bf16* sb = Xb + (size_t)(m0 + 64 + srow) * CC + k0 + scol;
      *(bf16x8*)&Ab[srow*LP + scol]     = ((const bf16x8*)sb)[0];
      *(bf16x8*)&Ab[srow*LP + scol + 8] = ((const bf16x8*)sb)[1];
      const bf16* s1 = Wb + (size_t)(nf0 + srow) * CC + k0 + scol;
      *(bf16x8*)&Ba[srow*LP + scol]     = ((const bf16x8*)s1)[0];
      *(bf16x8*)&Ba[srow*LP + scol + 8] = ((const bf16x8*)s1)[1];
      const bf16* s2 = Wb + (size_t)(nf0 + 64 + srow) * CC + k0 + scol;
      *(bf16x8*)&Bb[srow*LP + scol]     = ((const bf16x8*)s2)[0];
      *(bf16x8*)&Bb[srow*LP + scol + 8] = ((const bf16x8*)s2)[1];
    }
    __syncthreads();
    #pragma unroll
    for (int c = 0; c < 2; ++c) {
      bf16x8 afa = *(const bf16x8*)&Aa[(w*16 + l15)*LP + c*32 + quad*8];
      bf16x8 afb = *(const bf16x8*)&Ab[(w*16 + l15)*LP + c*32 + quad*8];
      #pragma unroll
      for (int nt = 0; nt < 4; ++nt) {
        bf16x8 ba = *(const bf16x8*)&Ba[(nt*16 + l15)*LP + c*32 + quad*8];
        bf16x8 bb = *(const bf16x8*)&Bb[(nt*16 + l15)*LP + c*32 + quad*8];
        acc[0][0][nt] = __builtin_amdgcn_mfma_f32_16x16x32_bf16(afa, ba, acc[0][0][nt], 0, 0, 0);
        acc[1][0][nt] = __builtin_amdgcn_mfma_f32_16x16x32_bf16(afb, ba, acc[1][0][nt], 0, 0, 0);
        acc[0][1][nt] = __builtin_amdgcn_mfma_f32_16x16x32_bf16(afa, bb, acc[0][1][nt], 0, 0, 0);
        acc[1][1][nt] = __builtin_amdgcn_mfma_f32_16x16x32_bf16(afb, bb, acc[1][1][nt], 0, 0, 0);
      }
    }
  }

  bf16* plane = (tens == 0) ? qp : ((tens == 1) ? kp : vtp);
  const int c8 = (t & 7) * 8;

  auto epi = [&](const f32x4* as, int mt0, int nb) {
    const int b = mt0 >> 12, s0g = mt0 & 4095;
    const int h = nb >> 6;
    __syncthreads();
    if (tens < 2) {
      #pragma unroll
      for (int nt = 0; nt < 4; ++nt)
        #pragma unroll
        for (int r = 0; r < 4; ++r)
          Aa[(w*16 + quad*4 + r)*LP + nt*16 + l15] = (bf16)as[nt][r];
    } else {
      #pragma unroll
      for (int nt = 0; nt < 4; ++nt)
        #pragma unroll
        for (int r = 0; r < 4; ++r)
          Aa[(nt*16 + l15)*LP + w*16 + quad*4 + r] = (bf16)as[nt][r];
    }
    __syncthreads();
    #pragma unroll
    for (int i = 0; i < 2; ++i) {
      const int row = (t >> 3) + 32*i;
      bf16x8 v = *(const bf16x8*)&Aa[row*LP + c8];
      if (tens < 2) {
        *(bf16x8*)&plane[((size_t)((b*HH + h)*SS) + s0g + row)*DD + c8] = v;
      } else {
        *(bf16x8*)&plane[((size_t)((b*HH + h)*DD) + row)*SS + s0g + c8] = v;
      }
    }
  };

  epi(acc[0][0], m0,      n0);
  epi(acc[1][0], m0 + 64, n0);
  epi(acc[0][1], m0,      n0 + 64);
  epi(acc[1][1], m0 + 64, n0 + 64);
}

// ---------------------------------------------------------------------------
// Kernel 2: flash attention — R4 deltas on the R3 split-K structure:
//  (a) V fragments read DIRECTLY from global vtp (L2-resident per XCD) —
//      V LDS tile + V staging + V prefetch deleted. Mapping is the exact
//      inverse of the proven staging permutation: vf = V[d=nt*16+l15,
//      k = kb + kbh*32 + quad*4 + {0..3}] ++ {+16..+19}. Halves LDS traffic
//      (the 50% pipe) and halves staging writes.
//  (b) s_setprio(1) around QK and PV MFMA clusters (T5) — lets the
//      MFMA-phase block win issue vs the exp-phase block (2 blocks/CU).
//  (c) kbh=1 V loads issued after PV kbh=0 to cap live VGPRs.
// LDS now: per-group K double-buffer only (36.9 KB total), stash overlays.
// ---------------------------------------------------------------------------
__global__ __launch_bounds__(512, 4) void attn_fa(
    const bf16* __restrict__ qpl, const bf16* __restrict__ kpl,
    const bf16* __restrict__ vtpl, bf16* __restrict__ aout)
{
  // per group: K dbuf (2 tiles of 64*LP bf16); stash overlays after the loop
  __shared__ __align__(16) bf16 smem[2 * 2 * 64 * LP];   // 36864 B

  const int t = threadIdx.x;
  const int w = t >> 6;                  // 0..7
  const int g = w >> 2;                  // k-group
  const int wl = w & 3;                  // wave within group -> q-strip
  const int lane = t & 63;
  const int l15 = lane & 15;
  const int quad = lane >> 4;

  const int lin = blockIdx.x;            // 0..511
  const int bh = lin & 15;               // fastest -> same XCD class per bh
  const int q0 = (lin >> 4) * 128;
  const size_t plane = (size_t)SS * DD;
  const bf16* Qp = qpl + (size_t)bh * plane;
  const bf16* Kp = kpl + (size_t)bh * plane;
  const bf16* Vg = vtpl + (size_t)bh * plane;

  bf16* Ktg = smem + g * (2*64*LP);      // K tiles buf0, buf1

  bf16x8 qf[2][2];
  #pragma unroll
  for (int wq = 0; wq < 2; ++wq) {
    const bf16* qr = Qp + (size_t)(q0 + wl*32 + wq*16 + l15) * DD + quad*8;
    qf[wq][0] = *(const bf16x8*)qr;
    qf[wq][1] = *(const bf16x8*)(qr + 32);
  }

  f32x4 o[2][4];
  float rs[2] = {0.f, 0.f};
  #pragma unroll
  for (int wq = 0; wq < 2; ++wq)
    #pragma unroll
    for (int nt = 0; nt < 4; ++nt)
      #pragma unroll
      for (int r = 0; r < 4; ++r) o[wq][nt][r] = 0.f;

  // K staging: 256 threads per group; each stages one K row-chunk (16 cols).
  const int t8  = t & 255;
  const int r0s = t8 >> 2;               // 0..63
  const int cs  = (t8 & 3) << 4;         // {0,16,32,48}
  const int kbase = g << 11;             // g*2048

  bf16x8 ka0, ka1;
  {
    ka0 = *(const bf16x8*)&Kp[(size_t)(kbase + r0s)*DD + cs];
    ka1 = *(const bf16x8*)&Kp[(size_t)(kbase + r0s)*DD + cs + 8];
    *(bf16x8*)&Ktg[r0s*LP + cs]     = ka0;
    *(bf16x8*)&Ktg[r0s*LP + cs + 8] = ka1;
  }
  __syncthreads();

  // V row base for this lane's fragments (d-row = nt*16 + l15)
  const bf16* Vrow = Vg + (size_t)l15 * SS;

  for (int it = 0; it < 32; ++it) {
    const int cur = it & 1;
    const int kb = kbase + it * 64;
    if (it < 31) {
      const int kn = kb + 64;
      ka0 = *(const bf16x8*)&Kp[(size_t)(kn + r0s)*DD + cs];
      ka1 = *(const bf16x8*)&Kp[(size_t)(kn + r0s)*DD + cs + 8];
    }

    // V loads for kbh=0 of the CURRENT tile (covered by QK+exp latency)
    bf16x4 vl0[4], vh0[4];
    #pragma unroll
    for (int nt = 0; nt < 4; ++nt) {
      const bf16* vp = Vrow + (size_t)(nt*16) * SS + kb + quad*4;
      vl0[nt] = *(const bf16x4*)vp;
      vh0[nt] = *(const bf16x4*)(vp + 16);
    }

    const bf16* Ktc = Ktg + cur*(64*LP);

    f32x4 st[2][4];
    __builtin_amdgcn_s_setprio(1);
    #pragma unroll
    for (int nt = 0; nt < 4; ++nt) {
      bf16x8 kf0 = *(const bf16x8*)&Ktc[(nt*16 + l15)*LP + quad*8];
      bf16x8 kf1 = *(const bf16x8*)&Ktc[(nt*16 + l15)*LP + 32 + quad*8];
      #pragma unroll
      for (int wq = 0; wq < 2; ++wq) {
        f32x4 z; z[0]=z[1]=z[2]=z[3]=0.f;
        z = __builtin_amdgcn_mfma_f32_16x16x32_bf16(kf0, qf[wq][0], z, 0, 0, 0);
        z = __builtin_amdgcn_mfma_f32_16x16x32_bf16(kf1, qf[wq][1], z, 0, 0, 0);
        st[wq][nt] = z;
      }
    }
    __builtin_amdgcn_s_setprio(0);

    bf16x8 pb[2][2];
    #pragma unroll
    for (int wq = 0; wq < 2; ++wq) {
      float acc_s = 0.f;
      #pragma unroll
      for (int nt = 0; nt < 4; ++nt)
        #pragma unroll
        for (int r = 0; r < 4; ++r) {
          float pv = __builtin_amdgcn_exp2f(st[wq][nt][r]);
          acc_s += pv;
          pb[wq][nt >> 1][(nt & 1)*4 + r] = (bf16)pv;
        }
      rs[wq] += acc_s;
    }

    // PV kbh=0
    __builtin_amdgcn_s_setprio(1);
    #pragma unroll
    for (int nt = 0; nt < 4; ++nt) {
      bf16x8 vf = vcat(vl0[nt], vh0[nt]);
      #pragma unroll
      for (int wq = 0; wq < 2; ++wq)
        o[wq][nt] = __builtin_amdgcn_mfma_f32_16x16x32_bf16(vf, pb[wq][0], o[wq][nt], 0, 0, 0);
    }
    __builtin_amdgcn_s_setprio(0);

    // V loads for kbh=1 (covered by PV kbh=0)
    bf16x4 vl1[4], vh1[4];
    #pragma unroll
    for (int nt = 0; nt < 4; ++nt) {
      const bf16* vp = Vrow + (size_t)(nt*16) * SS + kb + 32 + quad*4;
      vl1[nt] = *(const bf16x4*)vp;
      vh1[nt] = *(const bf16x4*)(vp + 16);
    }

    // PV kbh=1
    __builtin_amdgcn_s_setprio(1);
    #pragma unroll
    for (int nt = 0; nt < 4; ++nt) {
      bf16x8 vf = vcat(vl1[nt], vh1[nt]);
      #pragma unroll
      for (int wq = 0; wq < 2; ++wq)
        o[wq][nt] = __builtin_amdgcn_mfma_f32_16x16x32_bf16(vf, pb[wq][1], o[wq][nt], 0, 0, 0);
    }
    __builtin_amdgcn_s_setprio(0);

    if (it < 31) {
      bf16* Ktn = Ktg + (cur ^ 1)*(64*LP);
      *(bf16x8*)&Ktn[r0s*LP + cs]     = ka0;
      *(bf16x8*)&Ktn[r0s*LP + cs + 8] = ka1;
      __syncthreads();
    }
  }

  // ---- combine the two k-groups, then normalize + write (group 0) ----
  __syncthreads();                       // all K LDS reads done
  float* stash = (float*)smem;           // 4 waves x 64 lanes x 36 floats
  const int sidx = (wl*64 + lane) * 36;  // 144 B/lane, 16B-aligned
  if (g == 1) {
    #pragma unroll
    for (int wq = 0; wq < 2; ++wq)
      #pragma unroll
      for (int nt = 0; nt < 4; ++nt)
        *(f32x4*)&stash[sidx + (wq*4 + nt)*4] = o[wq][nt];
    stash[sidx + 32] = rs[0];
    stash[sidx + 33] = rs[1];
  }
  __syncthreads();
  if (g == 0) {
    #pragma unroll
    for (int wq = 0; wq < 2; ++wq)
      #pragma unroll
      for (int nt = 0; nt < 4; ++nt) {
        f32x4 p = *(const f32x4*)&stash[sidx + (wq*4 + nt)*4];
        #pragma unroll
        for (int r = 0; r < 4; ++r) o[wq][nt][r] += p[r];
      }
    rs[0] += stash[sidx + 32];
    rs[1] += stash[sidx + 33];

    const int b = bh >> 3, h = bh & 7;
    #pragma unroll
    for (int wq = 0; wq < 2; ++wq) {
      float s = rs[wq];
      s += __shfl_xor(s, 16);
      s += __shfl_xor(s, 32);
      const float inv = 1.f / s;
      const size_t row = (size_t)(b*SS + q0 + wl*32 + wq*16 + l15) * CC + h*DD;
      #pragma unroll
      for (int nt = 0; nt < 4; ++nt) {
        bf16x4 ov;
        #pragma unroll
        for (int r = 0; r < 4; ++r) ov[r] = (bf16)(o[wq][nt][r] * inv);
        *(bf16x4*)&aout[row + nt*16 + quad*4] = ov;
      }
    }
  }
}

// ---------------------------------------------------------------------------
// Kernel 3: out = attn @ Wo^T + bo — VERBATIM R10 green (m-pair) source.
// ---------------------------------------------------------------------------
__global__ __launch_bounds__(256) void out_gemm(
    const bf16* __restrict__ A, const bf16* __restrict__ Wob,
    const float* __restrict__ bo, float* __restrict__ out)
{
  __shared__ bf16 Aa[64*LP];
  __shared__ bf16 Ab[64*LP];
  __shared__ bf16 Bt[64*LP];
  const int m0 = blockIdx.x * 128;         // pair: m0 and m0+64
  const int n0 = blockIdx.y * 64;

  const int t = threadIdx.x;
  const int w = t >> 6;
  const int lane = t & 63;
  const int l15 = lane & 15;
  const int quad = lane >> 4;
  const int srow = t >> 2;
  const int scol = (t & 3) << 4;

  f32x4 aca[4], acb[4];
  #pragma unroll
  for (int i = 0; i < 4; ++i)
    #pragma unroll
    for (int j = 0; j < 4; ++j) { aca[i][j] = 0.f; acb[i][j] = 0.f; }

  for (int k0 = 0; k0 < CC; k0 += 64) {
    __syncthreads();
    {
      const bf16* sa = A + (size_t)(m0 + srow) * CC + k0 + scol;
      *(bf16x8*)&Aa[srow*LP + scol]     = ((const bf16x8*)sa)[0];
      *(bf16x8*)&Aa[srow*LP + scol + 8] = ((const bf16x8*)sa)[1];
      const bf16* sb = A + (size_t)(m0 + 64 + srow) * CC + k0 + scol;
      *(bf16x8*)&Ab[srow*LP + scol]     = ((const bf16x8*)sb)[0];
      *(bf16x8*)&Ab[srow*LP + scol + 8] = ((const bf16x8*)sb)[1];
      const bf16* s1 = Wob + (size_t)(n0 + srow) * CC + k0 + scol;
      *(bf16x8*)&Bt[srow*LP + scol]     = ((const bf16x8*)s1)[0];
      *(bf16x8*)&Bt[srow*LP + scol + 8] = ((const bf16x8*)s1)[1];
    }
    __syncthreads();
    #pragma unroll
    for (int c = 0; c < 2; ++c) {
      bf16x8 afa = *(const bf16x8*)&Aa[(w*16 + l15)*LP + c*32 + quad*8];
      bf16x8 afb = *(const bf16x8*)&Ab[(w*16 + l15)*LP + c*32 + quad*8];
      #pragma unroll
      for (int nt = 0; nt < 4; ++nt) {
        bf16x8 bfr = *(const bf16x8*)&Bt[(nt*16 + l15)*LP + c*32 + quad*8];
        aca[nt] = __builtin_amdgcn_mfma_f32_16x16x32_bf16(afa, bfr, aca[nt], 0, 0, 0);
        acb[nt] = __builtin_amdgcn_mfma_f32_16x16x32_bf16(afb, bfr, acb[nt], 0, 0, 0);
      }
    }
  }

  #pragma unroll
  for (int nt = 0; nt < 4; ++nt) {
    const int ng = n0 + nt*16 + l15;
    const float bias = bo[ng];
    #pragma unroll
    for (int r = 0; r < 4; ++r) {
      const int mga = m0 + w*16 + quad*4 + r;
      out[(size_t)mga*CC + ng] = aca[nt][r] + bias;
      const int mgb = m0 + 64 + w*16 + quad*4 + r;
      out[(size_t)mgb*CC + ng] = acb[nt][r] + bias;
    }
  }
}

extern "C" void kernel_launch(void* const* d_in, const int* in_sizes, int n_in,
                              void* d_out, int out_size, void* d_ws, size_t ws_size,
                              hipStream_t stream) {
  const float* hs = (const float*)d_in[0];
  const float* Wq = (const float*)d_in[1];
  const float* Wk = (const float*)d_in[2];
  const float* Wv = (const float*)d_in[3];
  const float* Wo = (const float*)d_in[4];
  const float* bo = (const float*)d_in[5];
  float* out = (float*)d_out;

  const size_t PE = (size_t)BB*HH*SS*DD;      // 4,194,304 elems (8 MiB bf16)
  bf16* ws   = (bf16*)d_ws;
  bf16* qp   = ws;                 // [B][H][S][D] (scale folded via Wb)
  bf16* kp   = ws + PE;            // [B][H][S][D]
  bf16* vtp  = ws + 2*PE;          // [B][H][D][S]  (transposed)
  bf16* Xb   = ws + 3*PE;          // [MM][CC] bf16 (dead after qkv_gemm)
  bf16* aout = ws + 3*PE;          // [B][S][C]    (overwrites Xb after attn)
  bf16* Wob  = qp;                 // [CC][CC] bf16 (qp dead after attn)
  bf16* Wb   = ws + 4*PE;          // [1536][512] bf16 (ws >= 40.5 MB proven by R7)

  cvt_f32_bf16<<<dim3(2048),      256, 0, stream>>>(hs, Xb);        // X -> bf16
  cvt_w       <<<dim3(384),       256, 0, stream>>>(Wq, Wk, Wv, Wb);
  qkv_gemm<<<dim3(MM/128, 12),    256, 0, stream>>>(Xb, Wb, qp, kp, vtp);
  attn_fa <<<dim3(512),           512, 0, stream>>>(qp, kp, vtp, aout);
  cvt_f32_bf16<<<dim3(128),       256, 0, stream>>>(Wo, Wob);       // Wo -> bf16
  out_gemm<<<dim3(MM/128, CC/64), 256, 0, stream>>>(aout, Wob, bo, out);
}

// Round 6
// 285.920 us; speedup vs baseline: 1.3586x; 1.3586x over previous
//
#include <hip/hip_runtime.h>
#include <hip/hip_bf16.h>

#define BB 2
#define SS 4096
#define CC 512
#define HH 8
#define DD 64
#define MM (BB*SS)

typedef __bf16 bf16;
typedef __attribute__((ext_vector_type(8))) __bf16 bf16x8;
typedef __attribute__((ext_vector_type(4))) __bf16 bf16x4;
typedef __attribute__((ext_vector_type(4))) float f32x4;

#define LP 72  // LDS row stride (64 + 8 pad), multiple of 8 -> 16B-aligned rows
#define QSCALE 0.18033688f  // 1/sqrt(64) * log2(e), folded into Wq at cvt time

__device__ __forceinline__ bf16x8 cvt8(const float4 a, const float4 b) {
  bf16x8 r;
  r[0]=(bf16)a.x; r[1]=(bf16)a.y; r[2]=(bf16)a.z; r[3]=(bf16)a.w;
  r[4]=(bf16)b.x; r[5]=(bf16)b.y; r[6]=(bf16)b.z; r[7]=(bf16)b.w;
  return r;
}

// ---------------------------------------------------------------------------
// Kernel 0: elementwise fp32 -> bf16 (X, Wo).
// ---------------------------------------------------------------------------
__global__ __launch_bounds__(256) void cvt_f32_bf16(
    const float* __restrict__ src, bf16* __restrict__ dst)
{
  size_t e = ((size_t)blockIdx.x * 256 + threadIdx.x) * 8;
  float4 a = ((const float4*)(src + e))[0];
  float4 b = ((const float4*)(src + e))[1];
  *(bf16x8*)(dst + e) = cvt8(a, b);
}

// ---------------------------------------------------------------------------
// Kernel 0b: fused Wq|Wk|Wv -> bf16 [1536][512], QSCALE folded into Wq.
// ---------------------------------------------------------------------------
__global__ __launch_bounds__(256) void cvt_w(
    const float* __restrict__ Wq, const float* __restrict__ Wk,
    const float* __restrict__ Wv, bf16* __restrict__ Wb)
{
  size_t e = ((size_t)blockIdx.x * 256 + threadIdx.x) * 8;  // < 786432
  const int tens = (int)(e >> 18);                          // 262144 per W
  const float* src = ((tens == 0) ? Wq : (tens == 1) ? Wk : Wv) + (e & 262143);
  const float sc = (tens == 0) ? QSCALE : 1.f;
  float4 a = ((const float4*)src)[0];
  float4 b = ((const float4*)src)[1];
  bf16x8 r;
  r[0]=(bf16)(a.x*sc); r[1]=(bf16)(a.y*sc); r[2]=(bf16)(a.z*sc); r[3]=(bf16)(a.w*sc);
  r[4]=(bf16)(b.x*sc); r[5]=(bf16)(b.y*sc); r[6]=(bf16)(b.z*sc); r[7]=(bf16)(b.w*sc);
  *(bf16x8*)(Wb + e) = r;
}

// ---------------------------------------------------------------------------
// Kernel 1: fused QKV projection — R10 green, with ONE delta: the V (tens==2)
// epilogue stores a FRAGMENT-PACKED layout vfp[bh][kb64][kbh][nt][lane][j]
// (exact inverse of the R3-proven LDS staging permutation:
//  k = kb*64 + kbh*32 + quad*4 + (j&3) + (j>>2)*16, lane = quad*16 + (d&15)),
// so attn_fa can read PV operands as contiguous coalesced bf16x8.
// ---------------------------------------------------------------------------
__global__ __launch_bounds__(256) void qkv_gemm(
    const bf16* __restrict__ Xb, const bf16* __restrict__ Wb,
    bf16* __restrict__ qp, bf16* __restrict__ kp, bf16* __restrict__ vtp)
{
  __shared__ bf16 Aa[64*LP];
  __shared__ bf16 Ab[64*LP];
  __shared__ bf16 Ba[64*LP];
  __shared__ bf16 Bb[64*LP];
  const int m0  = blockIdx.x * 128;        // m-pair: m0, m0+64
  const int nf0 = blockIdx.y * 128;        // n-pair within fused [0,1536)
  const int tens = nf0 >> 9;               // 128 divides 512 -> uniform
  const int n0 = nf0 & 511;                // first n-strip; second is n0+64

  const int t = threadIdx.x;
  const int w = t >> 6;
  const int lane = t & 63;
  const int l15 = lane & 15;
  const int quad = lane >> 4;
  const int srow = t >> 2;
  const int scol = (t & 3) << 4;

  f32x4 acc[2][2][4];  // [mi][ni][nt]
  #pragma unroll
  for (int mi = 0; mi < 2; ++mi)
    #pragma unroll
    for (int ni = 0; ni < 2; ++ni)
      #pragma unroll
      for (int nt = 0; nt < 4; ++nt)
        #pragma unroll
        for (int r = 0; r < 4; ++r) acc[mi][ni][nt][r] = 0.f;

  for (int k0 = 0; k0 < CC; k0 += 64) {
    __syncthreads();
    {
      const bf16* sa = Xb + (size_t)(m0 + srow) * CC + k0 + scol;
      *(bf16x8*)&Aa[srow*LP + scol]     = ((const bf16x8*)sa)[0];
      *(bf16x8*)&Aa[srow*LP + scol + 8] = ((const bf16x8*)sa)[1];
      const bf16* sb = Xb + (size_t)(m0 + 64 + srow) * CC + k0 + scol;
      *(bf16x8*)&Ab[srow*LP + scol]     = ((const bf16x8*)sb)[0];
      *(bf16x8*)&Ab[srow*LP + scol + 8] = ((const bf16x8*)sb)[1];
      const bf16* s1 = Wb + (size_t)(nf0 + srow) * CC + k0 + scol;
      *(bf16x8*)&Ba[srow*LP + scol]     = ((const bf16x8*)s1)[0];
      *(bf16x8*)&Ba[srow*LP + scol + 8] = ((const bf16x8*)s1)[1];
      const bf16* s2 = Wb + (size_t)(nf0 + 64 + srow) * CC + k0 + scol;
      *(bf16x8*)&Bb[srow*LP + scol]     = ((const bf16x8*)s2)[0];
      *(bf16x8*)&Bb[srow*LP + scol + 8] = ((const bf16x8*)s2)[1];
    }
    __syncthreads();
    #pragma unroll
    for (int c = 0; c < 2; ++c) {
      bf16x8 afa = *(const bf16x8*)&Aa[(w*16 + l15)*LP + c*32 + quad*8];
      bf16x8 afb = *(const bf16x8*)&Ab[(w*16 + l15)*LP + c*32 + quad*8];
      #pragma unroll
      for (int nt = 0; nt < 4; ++nt) {
        bf16x8 ba = *(const bf16x8*)&Ba[(nt*16 + l15)*LP + c*32 + quad*8];
        bf16x8 bb = *(const bf16x8*)&Bb[(nt*16 + l15)*LP + c*32 + quad*8];
        acc[0][0][nt] = __builtin_amdgcn_mfma_f32_16x16x32_bf16(afa, ba, acc[0][0][nt], 0, 0, 0);
        acc[1][0][nt] = __builtin_amdgcn_mfma_f32_16x16x32_bf16(afb, ba, acc[1][0][nt], 0, 0, 0);
        acc[0][1][nt] = __builtin_amdgcn_mfma_f32_16x16x32_bf16(afa, bb, acc[0][1][nt], 0, 0, 0);
        acc[1][1][nt] = __builtin_amdgcn_mfma_f32_16x16x32_bf16(afb, bb, acc[1][1][nt], 0, 0, 0);
      }
    }
  }

  bf16* plane = (tens == 0) ? qp : ((tens == 1) ? kp : vtp);
  const int c8 = (t & 7) * 8;

  auto epi = [&](const f32x4* as, int mt0, int nb) {
    const int b = mt0 >> 12, s0g = mt0 & 4095;
    const int h = nb >> 6;
    __syncthreads();
    if (tens < 2) {
      #pragma unroll
      for (int nt = 0; nt < 4; ++nt)
        #pragma unroll
        for (int r = 0; r < 4; ++r)
          Aa[(w*16 + quad*4 + r)*LP + nt*16 + l15] = (bf16)as[nt][r];
    } else {
      #pragma unroll
      for (int nt = 0; nt < 4; ++nt)
        #pragma unroll
        for (int r = 0; r < 4; ++r)
          Aa[(nt*16 + l15)*LP + w*16 + quad*4 + r] = (bf16)as[nt][r];
    }
    __syncthreads();
    #pragma unroll
    for (int i = 0; i < 2; ++i) {
      const int row = (t >> 3) + 32*i;
      bf16x8 v = *(const bf16x8*)&Aa[row*LP + c8];
      if (tens < 2) {
        *(bf16x8*)&plane[((size_t)((b*HH + h)*SS) + s0g + row)*DD + c8] = v;
      } else {
        // fragment-packed V store (2 x 8B): thread holds V[d=row][s0g+c8+j]
        const int kb    = s0g >> 6;          // s0g is a multiple of 64, c8 < 64
        const int kbh   = c8 >> 5;
        const int rr0   = c8 & 31;           // {0,8,16,24}
        const int quadA = (rr0 & 15) >> 2;   // 0 or 2
        const int hi4   = (rr0 >> 4) << 2;   // 0 or 4
        const int ntv   = row >> 4;
        const int l15v  = row & 15;
        bf16* fb = plane +
            ((((size_t)((b*HH + h)*64 + kb))*2 + kbh)*4 + ntv)*512;
        bf16x4 lo, hi;
        lo[0]=v[0]; lo[1]=v[1]; lo[2]=v[2]; lo[3]=v[3];
        hi[0]=v[4]; hi[1]=v[5]; hi[2]=v[6]; hi[3]=v[7];
        *(bf16x4*)&fb[(quadA*16 + l15v)*8 + hi4]     = lo;
        *(bf16x4*)&fb[((quadA+1)*16 + l15v)*8 + hi4] = hi;
      }
    }
  };

  epi(acc[0][0], m0,      n0);
  epi(acc[1][0], m0 + 64, n0);
  epi(acc[0][1], m0,      n0 + 64);
  epi(acc[1][1], m0 + 64, n0 + 64);
}

// ---------------------------------------------------------------------------
// Kernel 2: flash attention — R5: R3 split-K structure (2 k-groups x 4 waves,
// Nq=32/wave, K double-buffered in LDS) with V read DIRECTLY from the
// fragment-packed vfp layout: vf[nt] is one contiguous 1KB coalesced bf16x8
// load per wave (L2-resident, 2 bh per XCD class). V LDS tile + V staging
// deleted -> LDS traffic halves again vs R3. s_setprio around MFMA clusters.
// ---------------------------------------------------------------------------
__global__ __launch_bounds__(512, 4) void attn_fa(
    const bf16* __restrict__ qpl, const bf16* __restrict__ kpl,
    const bf16* __restrict__ vtpl, bf16* __restrict__ aout)
{
  // per group: K dbuf (2 tiles of 64*LP bf16); stash overlays after the loop
  __shared__ __align__(16) bf16 smem[2 * 2 * 64 * LP];   // 36864 B

  const int t = threadIdx.x;
  const int w = t >> 6;                  // 0..7
  const int g = w >> 2;                  // k-group
  const int wl = w & 3;                  // wave within group -> q-strip
  const int lane = t & 63;
  const int l15 = lane & 15;
  const int quad = lane >> 4;

  const int lin = blockIdx.x;            // 0..511
  const int bh = lin & 15;               // fastest -> same XCD class per bh
  const int q0 = (lin >> 4) * 128;
  const size_t plane = (size_t)SS * DD;
  const bf16* Qp = qpl + (size_t)bh * plane;
  const bf16* Kp = kpl + (size_t)bh * plane;
  const bf16* Vfp = vtpl + (size_t)bh * plane;   // fragment-packed V plane

  bf16* Ktg = smem + g * (2*64*LP);      // K tiles buf0, buf1

  bf16x8 qf[2][2];
  #pragma unroll
  for (int wq = 0; wq < 2; ++wq) {
    const bf16* qr = Qp + (size_t)(q0 + wl*32 + wq*16 + l15) * DD + quad*8;
    qf[wq][0] = *(const bf16x8*)qr;
    qf[wq][1] = *(const bf16x8*)(qr + 32);
  }

  f32x4 o[2][4];
  float rs[2] = {0.f, 0.f};
  #pragma unroll
  for (int wq = 0; wq < 2; ++wq)
    #pragma unroll
    for (int nt = 0; nt < 4; ++nt)
      #pragma unroll
      for (int r = 0; r < 4; ++r) o[wq][nt][r] = 0.f;

  // K staging: 256 threads per group; each stages one K row-chunk (16 cols).
  const int t8  = t & 255;
  const int r0s = t8 >> 2;               // 0..63
  const int cs  = (t8 & 3) << 4;         // {0,16,32,48}
  const int kbase = g << 11;             // g*2048

  bf16x8 ka0, ka1;
  {
    ka0 = *(const bf16x8*)&Kp[(size_t)(kbase + r0s)*DD + cs];
    ka1 = *(const bf16x8*)&Kp[(size_t)(kbase + r0s)*DD + cs + 8];
    *(bf16x8*)&Ktg[r0s*LP + cs]     = ka0;
    *(bf16x8*)&Ktg[r0s*LP + cs + 8] = ka1;
  }
  __syncthreads();

  for (int it = 0; it < 32; ++it) {
    const int cur = it & 1;
    if (it < 31) {
      const int kn = kbase + (it + 1) * 64;
      ka0 = *(const bf16x8*)&Kp[(size_t)(kn + r0s)*DD + cs];
      ka1 = *(const bf16x8*)&Kp[(size_t)(kn + r0s)*DD + cs + 8];
    }

    // V fragment base for this k-block (4096 elems per kb entry)
    const bf16* ft = Vfp + (size_t)(g*32 + it) * 4096 + lane*8;

    // kbh=0 V fragments — contiguous 1KB coalesced loads, covered by QK+exp
    bf16x8 vf0[4];
    #pragma unroll
    for (int nt = 0; nt < 4; ++nt) vf0[nt] = *(const bf16x8*)&ft[nt*512];

    const bf16* Ktc = Ktg + cur*(64*LP);

    f32x4 st[2][4];
    __builtin_amdgcn_s_setprio(1);
    #pragma unroll
    for (int nt = 0; nt < 4; ++nt) {
      bf16x8 kf0 = *(const bf16x8*)&Ktc[(nt*16 + l15)*LP + quad*8];
      bf16x8 kf1 = *(const bf16x8*)&Ktc[(nt*16 + l15)*LP + 32 + quad*8];
      #pragma unroll
      for (int wq = 0; wq < 2; ++wq) {
        f32x4 z; z[0]=z[1]=z[2]=z[3]=0.f;
        z = __builtin_amdgcn_mfma_f32_16x16x32_bf16(kf0, qf[wq][0], z, 0, 0, 0);
        z = __builtin_amdgcn_mfma_f32_16x16x32_bf16(kf1, qf[wq][1], z, 0, 0, 0);
        st[wq][nt] = z;
      }
    }
    __builtin_amdgcn_s_setprio(0);

    // kbh=1 V fragments — covered by exp + PV kbh=0
    bf16x8 vf1[4];
    #pragma unroll
    for (int nt = 0; nt < 4; ++nt) vf1[nt] = *(const bf16x8*)&ft[(4 + nt)*512];

    bf16x8 pb[2][2];
    #pragma unroll
    for (int wq = 0; wq < 2; ++wq) {
      float acc_s = 0.f;
      #pragma unroll
      for (int nt = 0; nt < 4; ++nt)
        #pragma unroll
        for (int r = 0; r < 4; ++r) {
          float pv = __builtin_amdgcn_exp2f(st[wq][nt][r]);
          acc_s += pv;
          pb[wq][nt >> 1][(nt & 1)*4 + r] = (bf16)pv;
        }
      rs[wq] += acc_s;
    }

    __builtin_amdgcn_s_setprio(1);
    #pragma unroll
    for (int nt = 0; nt < 4; ++nt) {
      #pragma unroll
      for (int wq = 0; wq < 2; ++wq)
        o[wq][nt] = __builtin_amdgcn_mfma_f32_16x16x32_bf16(vf0[nt], pb[wq][0], o[wq][nt], 0, 0, 0);
    }
    #pragma unroll
    for (int nt = 0; nt < 4; ++nt) {
      #pragma unroll
      for (int wq = 0; wq < 2; ++wq)
        o[wq][nt] = __builtin_amdgcn_mfma_f32_16x16x32_bf16(vf1[nt], pb[wq][1], o[wq][nt], 0, 0, 0);
    }
    __builtin_amdgcn_s_setprio(0);

    if (it < 31) {
      bf16* Ktn = Ktg + (cur ^ 1)*(64*LP);
      *(bf16x8*)&Ktn[r0s*LP + cs]     = ka0;
      *(bf16x8*)&Ktn[r0s*LP + cs + 8] = ka1;
      __syncthreads();
    }
  }

  // ---- combine the two k-groups, then normalize + write (group 0) ----
  __syncthreads();                       // all K LDS reads done
  float* stash = (float*)smem;           // 4 waves x 64 lanes x 36 floats
  const int sidx = (wl*64 + lane) * 36;  // 144 B/lane, 16B-aligned
  if (g == 1) {
    #pragma unroll
    for (int wq = 0; wq < 2; ++wq)
      #pragma unroll
      for (int nt = 0; nt < 4; ++nt)
        *(f32x4*)&stash[sidx + (wq*4 + nt)*4] = o[wq][nt];
    stash[sidx + 32] = rs[0];
    stash[sidx + 33] = rs[1];
  }
  __syncthreads();
  if (g == 0) {
    #pragma unroll
    for (int wq = 0; wq < 2; ++wq)
      #pragma unroll
      for (int nt = 0; nt < 4; ++nt) {
        f32x4 p = *(const f32x4*)&stash[sidx + (wq*4 + nt)*4];
        #pragma unroll
        for (int r = 0; r < 4; ++r) o[wq][nt][r] += p[r];
      }
    rs[0] += stash[sidx + 32];
    rs[1] += stash[sidx + 33];

    const int b = bh >> 3, h = bh & 7;
    #pragma unroll
    for (int wq = 0; wq < 2; ++wq) {
      float s = rs[wq];
      s += __shfl_xor(s, 16);
      s += __shfl_xor(s, 32);
      const float inv = 1.f / s;
      const size_t row = (size_t)(b*SS + q0 + wl*32 + wq*16 + l15) * CC + h*DD;
      #pragma unroll
      for (int nt = 0; nt < 4; ++nt) {
        bf16x4 ov;
        #pragma unroll
        for (int r = 0; r < 4; ++r) ov[r] = (bf16)(o[wq][nt][r] * inv);
        *(bf16x4*)&aout[row + nt*16 + quad*4] = ov;
      }
    }
  }
}

// ---------------------------------------------------------------------------
// Kernel 3: out = attn @ Wo^T + bo — VERBATIM R10 green (m-pair) source.
// ---------------------------------------------------------------------------
__global__ __launch_bounds__(256) void out_gemm(
    const bf16* __restrict__ A, const bf16* __restrict__ Wob,
    const float* __restrict__ bo, float* __restrict__ out)
{
  __shared__ bf16 Aa[64*LP];
  __shared__ bf16 Ab[64*LP];
  __shared__ bf16 Bt[64*LP];
  const int m0 = blockIdx.x * 128;         // pair: m0 and m0+64
  const int n0 = blockIdx.y * 64;

  const int t = threadIdx.x;
  const int w = t >> 6;
  const int lane = t & 63;
  const int l15 = lane & 15;
  const int quad = lane >> 4;
  const int srow = t >> 2;
  const int scol = (t & 3) << 4;

  f32x4 aca[4], acb[4];
  #pragma unroll
  for (int i = 0; i < 4; ++i)
    #pragma unroll
    for (int j = 0; j < 4; ++j) { aca[i][j] = 0.f; acb[i][j] = 0.f; }

  for (int k0 = 0; k0 < CC; k0 += 64) {
    __syncthreads();
    {
      const bf16* sa = A + (size_t)(m0 + srow) * CC + k0 + scol;
      *(bf16x8*)&Aa[srow*LP + scol]     = ((const bf16x8*)sa)[0];
      *(bf16x8*)&Aa[srow*LP + scol + 8] = ((const bf16x8*)sa)[1];
      const bf16* sb = A + (size_t)(m0 + 64 + srow) * CC + k0 + scol;
      *(bf16x8*)&Ab[srow*LP + scol]     = ((const bf16x8*)sb)[0];
      *(bf16x8*)&Ab[srow*LP + scol + 8] = ((const bf16x8*)sb)[1];
      const bf16* s1 = Wob + (size_t)(n0 + srow) * CC + k0 + scol;
      *(bf16x8*)&Bt[srow*LP + scol]     = ((const bf16x8*)s1)[0];
      *(bf16x8*)&Bt[srow*LP + scol + 8] = ((const bf16x8*)s1)[1];
    }
    __syncthreads();
    #pragma unroll
    for (int c = 0; c < 2; ++c) {
      bf16x8 afa = *(const bf16x8*)&Aa[(w*16 + l15)*LP + c*32 + quad*8];
      bf16x8 afb = *(const bf16x8*)&Ab[(w*16 + l15)*LP + c*32 + quad*8];
      #pragma unroll
      for (int nt = 0; nt < 4; ++nt) {
        bf16x8 bfr = *(const bf16x8*)&Bt[(nt*16 + l15)*LP + c*32 + quad*8];
        aca[nt] = __builtin_amdgcn_mfma_f32_16x16x32_bf16(afa, bfr, aca[nt], 0, 0, 0);
        acb[nt] = __builtin_amdgcn_mfma_f32_16x16x32_bf16(afb, bfr, acb[nt], 0, 0, 0);
      }
    }
  }

  #pragma unroll
  for (int nt = 0; nt < 4; ++nt) {
    const int ng = n0 + nt*16 + l15;
    const float bias = bo[ng];
    #pragma unroll
    for (int r = 0; r < 4; ++r) {
      const int mga = m0 + w*16 + quad*4 + r;
      out[(size_t)mga*CC + ng] = aca[nt][r] + bias;
      const int mgb = m0 + 64 + w*16 + quad*4 + r;
      out[(size_t)mgb*CC + ng] = acb[nt][r] + bias;
    }
  }
}

extern "C" void kernel_launch(void* const* d_in, const int* in_sizes, int n_in,
                              void* d_out, int out_size, void* d_ws, size_t ws_size,
                              hipStream_t stream) {
  const float* hs = (const float*)d_in[0];
  const float* Wq = (const float*)d_in[1];
  const float* Wk = (const float*)d_in[2];
  const float* Wv = (const float*)d_in[3];
  const float* Wo = (const float*)d_in[4];
  const float* bo = (const float*)d_in[5];
  float* out = (float*)d_out;

  const size_t PE = (size_t)BB*HH*SS*DD;      // 4,194,304 elems (8 MiB bf16)
  bf16* ws   = (bf16*)d_ws;
  bf16* qp   = ws;                 // [B][H][S][D] (scale folded via Wb)
  bf16* kp   = ws + PE;            // [B][H][S][D]
  bf16* vtp  = ws + 2*PE;          // fragment-packed V: [bh][kb64][kbh][nt][lane][8]
  bf16* Xb   = ws + 3*PE;          // [MM][CC] bf16 (dead after qkv_gemm)
  bf16* aout = ws + 3*PE;          // [B][S][C]    (overwrites Xb after attn)
  bf16* Wob  = qp;                 // [CC][CC] bf16 (qp dead after attn)
  bf16* Wb   = ws + 4*PE;          // [1536][512] bf16 (ws >= 40.5 MB proven by R7)

  cvt_f32_bf16<<<dim3(2048),      256, 0, stream>>>(hs, Xb);        // X -> bf16
  cvt_w       <<<dim3(384),       256, 0, stream>>>(Wq, Wk, Wv, Wb);
  qkv_gemm<<<dim3(MM/128, 12),    256, 0, stream>>>(Xb, Wb, qp, kp, vtp);
  attn_fa <<<dim3(512),           512, 0, stream>>>(qp, kp, vtp, aout);
  cvt_f32_bf16<<<dim3(128),       256, 0, stream>>>(Wo, Wob);       // Wo -> bf16
  out_gemm<<<dim3(MM/128, CC/64), 256, 0, stream>>>(aout, Wob, bo, out);
}

// Round 7
// 187.115 us; speedup vs baseline: 2.0760x; 1.5280x over previous
//
#include <hip/hip_runtime.h>
#include <hip/hip_bf16.h>

#define BB 2
#define SS 4096
#define CC 512
#define HH 8
#define DD 64
#define MM (BB*SS)

typedef __bf16 bf16;
typedef __attribute__((ext_vector_type(8))) __bf16 bf16x8;
typedef __attribute__((ext_vector_type(4))) __bf16 bf16x4;
typedef __attribute__((ext_vector_type(4))) float f32x4;

#define LP 72  // LDS row stride (64 + 8 pad), multiple of 8 -> 16B-aligned rows
#define QSCALE 0.18033688f  // 1/sqrt(64) * log2(e), folded into Wq at cvt time

__device__ __forceinline__ bf16x8 cvt8(const float4 a, const float4 b) {
  bf16x8 r;
  r[0]=(bf16)a.x; r[1]=(bf16)a.y; r[2]=(bf16)a.z; r[3]=(bf16)a.w;
  r[4]=(bf16)b.x; r[5]=(bf16)b.y; r[6]=(bf16)b.z; r[7]=(bf16)b.w;
  return r;
}

// ---------------------------------------------------------------------------
// Kernel 0: elementwise fp32 -> bf16 (X, Wo).
// ---------------------------------------------------------------------------
__global__ __launch_bounds__(256) void cvt_f32_bf16(
    const float* __restrict__ src, bf16* __restrict__ dst)
{
  size_t e = ((size_t)blockIdx.x * 256 + threadIdx.x) * 8;
  float4 a = ((const float4*)(src + e))[0];
  float4 b = ((const float4*)(src + e))[1];
  *(bf16x8*)(dst + e) = cvt8(a, b);
}

// ---------------------------------------------------------------------------
// Kernel 0b: fused Wq|Wk|Wv -> bf16 [1536][512], QSCALE folded into Wq.
// ---------------------------------------------------------------------------
__global__ __launch_bounds__(256) void cvt_w(
    const float* __restrict__ Wq, const float* __restrict__ Wk,
    const float* __restrict__ Wv, bf16* __restrict__ Wb)
{
  size_t e = ((size_t)blockIdx.x * 256 + threadIdx.x) * 8;  // < 786432
  const int tens = (int)(e >> 18);                          // 262144 per W
  const float* src = ((tens == 0) ? Wq : (tens == 1) ? Wk : Wv) + (e & 262143);
  const float sc = (tens == 0) ? QSCALE : 1.f;
  float4 a = ((const float4*)src)[0];
  float4 b = ((const float4*)src)[1];
  bf16x8 r;
  r[0]=(bf16)(a.x*sc); r[1]=(bf16)(a.y*sc); r[2]=(bf16)(a.z*sc); r[3]=(bf16)(a.w*sc);
  r[4]=(bf16)(b.x*sc); r[5]=(bf16)(b.y*sc); r[6]=(bf16)(b.z*sc); r[7]=(bf16)(b.w*sc);
  *(bf16x8*)(Wb + e) = r;
}

// ---------------------------------------------------------------------------
// Kernel 1: fused QKV projection — VERBATIM R10 green (2x2 mosaic, bf16).
// ---------------------------------------------------------------------------
__global__ __launch_bounds__(256) void qkv_gemm(
    const bf16* __restrict__ Xb, const bf16* __restrict__ Wb,
    bf16* __restrict__ qp, bf16* __restrict__ kp, bf16* __restrict__ vtp)
{
  __shared__ bf16 Aa[64*LP];
  __shared__ bf16 Ab[64*LP];
  __shared__ bf16 Ba[64*LP];
  __shared__ bf16 Bb[64*LP];
  const int m0  = blockIdx.x * 128;        // m-pair: m0, m0+64
  const int nf0 = blockIdx.y * 128;        // n-pair within fused [0,1536)
  const int tens = nf0 >> 9;               // 128 divides 512 -> uniform
  const int n0 = nf0 & 511;                // first n-strip; second is n0+64

  const int t = threadIdx.x;
  const int w = t >> 6;
  const int lane = t & 63;
  const int l15 = lane & 15;
  const int quad = lane >> 4;
  const int srow = t >> 2;
  const int scol = (t & 3) << 4;

  f32x4 acc[2][2][4];  // [mi][ni][nt]
  #pragma unroll
  for (int mi = 0; mi < 2; ++mi)
    #pragma unroll
    for (int ni = 0; ni < 2; ++ni)
      #pragma unroll
      for (int nt = 0; nt < 4; ++nt)
        #pragma unroll
        for (int r = 0; r < 4; ++r) acc[mi][ni][nt][r] = 0.f;

  for (int k0 = 0; k0 < CC; k0 += 64) {
    __syncthreads();
    {
      const bf16* sa = Xb + (size_t)(m0 + srow) * CC + k0 + scol;
      *(bf16x8*)&Aa[srow*LP + scol]     = ((const bf16x8*)sa)[0];
      *(bf16x8*)&Aa[srow*LP + scol + 8] = ((const bf16x8*)sa)[1];
      const bf16* sb = Xb + (size_t)(m0 + 64 + srow) * CC + k0 + scol;
      *(bf16x8*)&Ab[srow*LP + scol]     = ((const bf16x8*)sb)[0];
      *(bf16x8*)&Ab[srow*LP + scol + 8] = ((const bf16x8*)sb)[1];
      const bf16* s1 = Wb + (size_t)(nf0 + srow) * CC + k0 + scol;
      *(bf16x8*)&Ba[srow*LP + scol]     = ((const bf16x8*)s1)[0];
      *(bf16x8*)&Ba[srow*LP + scol + 8] = ((const bf16x8*)s1)[1];
      const bf16* s2 = Wb + (size_t)(nf0 + 64 + srow) * CC + k0 + scol;
      *(bf16x8*)&Bb[srow*LP + scol]     = ((const bf16x8*)s2)[0];
      *(bf16x8*)&Bb[srow*LP + scol + 8] = ((const bf16x8*)s2)[1];
    }
    __syncthreads();
    #pragma unroll
    for (int c = 0; c < 2; ++c) {
      bf16x8 afa = *(const bf16x8*)&Aa[(w*16 + l15)*LP + c*32 + quad*8];
      bf16x8 afb = *(const bf16x8*)&Ab[(w*16 + l15)*LP + c*32 + quad*8];
      #pragma unroll
      for (int nt = 0; nt < 4; ++nt) {
        bf16x8 ba = *(const bf16x8*)&Ba[(nt*16 + l15)*LP + c*32 + quad*8];
        bf16x8 bb = *(const bf16x8*)&Bb[(nt*16 + l15)*LP + c*32 + quad*8];
        acc[0][0][nt] = __builtin_amdgcn_mfma_f32_16x16x32_bf16(afa, ba, acc[0][0][nt], 0, 0, 0);
        acc[1][0][nt] = __builtin_amdgcn_mfma_f32_16x16x32_bf16(afb, ba, acc[1][0][nt], 0, 0, 0);
        acc[0][1][nt] = __builtin_amdgcn_mfma_f32_16x16x32_bf16(afa, bb, acc[0][1][nt], 0, 0, 0);
        acc[1][1][nt] = __builtin_amdgcn_mfma_f32_16x16x32_bf16(afb, bb, acc[1][1][nt], 0, 0, 0);
      }
    }
  }

  bf16* plane = (tens == 0) ? qp : ((tens == 1) ? kp : vtp);
  const int c8 = (t & 7) * 8;

  auto epi = [&](const f32x4* as, int mt0, int nb) {
    const int b = mt0 >> 12, s0g = mt0 & 4095;
    const int h = nb >> 6;
    __syncthreads();
    if (tens < 2) {
      #pragma unroll
      for (int nt = 0; nt < 4; ++nt)
        #pragma unroll
        for (int r = 0; r < 4; ++r)
          Aa[(w*16 + quad*4 + r)*LP + nt*16 + l15] = (bf16)as[nt][r];
    } else {
      #pragma unroll
      for (int nt = 0; nt < 4; ++nt)
        #pragma unroll
        for (int r = 0; r < 4; ++r)
          Aa[(nt*16 + l15)*LP + w*16 + quad*4 + r] = (bf16)as[nt][r];
    }
    __syncthreads();
    #pragma unroll
    for (int i = 0; i < 2; ++i) {
      const int row = (t >> 3) + 32*i;
      bf16x8 v = *(const bf16x8*)&Aa[row*LP + c8];
      if (tens < 2) {
        *(bf16x8*)&plane[((size_t)((b*HH + h)*SS) + s0g + row)*DD + c8] = v;
      } else {
        *(bf16x8*)&plane[((size_t)((b*HH + h)*DD) + row)*SS + s0g + c8] = v;
      }
    }
  };

  epi(acc[0][0], m0,      n0);
  epi(acc[1][0], m0 + 64, n0);
  epi(acc[0][1], m0,      n0 + 64);
  epi(acc[1][1], m0 + 64, n0 + 64);
}

// ---------------------------------------------------------------------------
// Kernel 2: flash attention — R6: VERBATIM R3 split-K structure (2 k-groups x
// 4 waves, Nq=32/wave, K AND V double-buffered in LDS — V-from-global failed
// twice: R4 scatter, R5 spill). Three local deltas:
//  (a) row-sum via ones-MFMA: osum[wq] = mfma(ones, pb, osum) replaces the
//      31-add fp32 tree + end shfl chain (C-layout: col=l15=q, so every lane
//      gets the full per-q sum; same bf16 pv as the numerator -> consistent).
//  (b) kbh-split exp->PV interleave: exp kbh0 -> PV kbh0 -> exp kbh1 -> PV
//      kbh1 (PV MFMA overlaps the other half's exp VALU).
//  (c) s_setprio(1) around MFMA clusters (T5).
// ---------------------------------------------------------------------------
__global__ __launch_bounds__(512, 4) void attn_fa(
    const bf16* __restrict__ qpl, const bf16* __restrict__ kpl,
    const bf16* __restrict__ vtpl, bf16* __restrict__ aout)
{
  // per group: K dbuf (2 tiles) + V dbuf (2 tiles), each tile 64*LP bf16
  __shared__ __align__(16) bf16 smem[2 * 4 * 64 * LP];   // 73728 B

  const int t = threadIdx.x;
  const int w = t >> 6;                  // 0..7
  const int g = w >> 2;                  // k-group
  const int wl = w & 3;                  // wave within group -> q-strip
  const int lane = t & 63;
  const int l15 = lane & 15;
  const int quad = lane >> 4;

  const int lin = blockIdx.x;            // 0..511
  const int bh = lin & 15;               // fastest -> same XCD class per bh
  const int q0 = (lin >> 4) * 128;
  const size_t plane = (size_t)SS * DD;
  const bf16* Qp = qpl + (size_t)bh * plane;
  const bf16* Kp = kpl + (size_t)bh * plane;
  const bf16* Vg = vtpl + (size_t)bh * plane;

  bf16* Ktg = smem + g * (4*64*LP);      // K tiles buf0, buf1
  bf16* Vtg = Ktg + 2*64*LP;             // V tiles buf0, buf1

  bf16x8 qf[2][2];
  #pragma unroll
  for (int wq = 0; wq < 2; ++wq) {
    const bf16* qr = Qp + (size_t)(q0 + wl*32 + wq*16 + l15) * DD + quad*8;
    qf[wq][0] = *(const bf16x8*)qr;
    qf[wq][1] = *(const bf16x8*)(qr + 32);
  }

  f32x4 o[2][4];
  f32x4 osum[2];
  #pragma unroll
  for (int wq = 0; wq < 2; ++wq) {
    #pragma unroll
    for (int nt = 0; nt < 4; ++nt)
      #pragma unroll
      for (int r = 0; r < 4; ++r) o[wq][nt][r] = 0.f;
    #pragma unroll
    for (int r = 0; r < 4; ++r) osum[wq][r] = 0.f;
  }

  bf16x8 ones;
  #pragma unroll
  for (int i = 0; i < 8; ++i) ones[i] = (bf16)1.0f;

  // staging: 256 threads per group; each stages one K row-chunk (16 cols)
  // and one V row-chunk (16 cols in fragment-permuted order).
  const int t8  = t & 255;
  const int r0s = t8 >> 2;               // 0..63
  const int cs  = (t8 & 3) << 4;         // {0,16,32,48}
  const int K0  = ((t8 & 1) << 3) + (((t8 >> 1) & 1) << 5);  // {0,8,32,40}
  const int kbase = g << 11;             // g*2048

  bf16x8 ka0, ka1, va, vb;
  {
    ka0 = *(const bf16x8*)&Kp[(size_t)(kbase + r0s)*DD + cs];
    ka1 = *(const bf16x8*)&Kp[(size_t)(kbase + r0s)*DD + cs + 8];
    va  = *(const bf16x8*)&Vg[(size_t)r0s*SS + kbase + K0];
    vb  = *(const bf16x8*)&Vg[(size_t)r0s*SS + kbase + K0 + 16];
    *(bf16x8*)&Ktg[r0s*LP + cs]     = ka0;
    *(bf16x8*)&Ktg[r0s*LP + cs + 8] = ka1;
    bf16x8 vv;
    vv[0]=va[0]; vv[1]=va[1]; vv[2]=va[2]; vv[3]=va[3];
    vv[4]=vb[0]; vv[5]=vb[1]; vv[6]=vb[2]; vv[7]=vb[3];
    *(bf16x8*)&Vtg[r0s*LP + cs] = vv;
    vv[0]=va[4]; vv[1]=va[5]; vv[2]=va[6]; vv[3]=va[7];
    vv[4]=vb[4]; vv[5]=vb[5]; vv[6]=vb[6]; vv[7]=vb[7];
    *(bf16x8*)&Vtg[r0s*LP + cs + 8] = vv;
  }
  __syncthreads();

  for (int it = 0; it < 32; ++it) {
    const int cur = it & 1;
    if (it < 31) {
      const int kn = kbase + (it + 1) * 64;
      ka0 = *(const bf16x8*)&Kp[(size_t)(kn + r0s)*DD + cs];
      ka1 = *(const bf16x8*)&Kp[(size_t)(kn + r0s)*DD + cs + 8];
      va  = *(const bf16x8*)&Vg[(size_t)r0s*SS + kn + K0];
      vb  = *(const bf16x8*)&Vg[(size_t)r0s*SS + kn + K0 + 16];
    }

    const bf16* Ktc = Ktg + cur*(64*LP);
    const bf16* Vtc = Vtg + cur*(64*LP);

    f32x4 st[2][4];
    __builtin_amdgcn_s_setprio(1);
    #pragma unroll
    for (int nt = 0; nt < 4; ++nt) {
      bf16x8 kf0 = *(const bf16x8*)&Ktc[(nt*16 + l15)*LP + quad*8];
      bf16x8 kf1 = *(const bf16x8*)&Ktc[(nt*16 + l15)*LP + 32 + quad*8];
      #pragma unroll
      for (int wq = 0; wq < 2; ++wq) {
        f32x4 z; z[0]=z[1]=z[2]=z[3]=0.f;
        z = __builtin_amdgcn_mfma_f32_16x16x32_bf16(kf0, qf[wq][0], z, 0, 0, 0);
        z = __builtin_amdgcn_mfma_f32_16x16x32_bf16(kf1, qf[wq][1], z, 0, 0, 0);
        st[wq][nt] = z;
      }
    }
    __builtin_amdgcn_s_setprio(0);

    // ---- kbh = 0: exp/pack nt 0..1, then PV ----
    bf16x8 pb0[2];
    #pragma unroll
    for (int wq = 0; wq < 2; ++wq)
      #pragma unroll
      for (int nt = 0; nt < 2; ++nt)
        #pragma unroll
        for (int r = 0; r < 4; ++r)
          pb0[wq][(nt & 1)*4 + r] = (bf16)__builtin_amdgcn_exp2f(st[wq][nt][r]);

    __builtin_amdgcn_s_setprio(1);
    #pragma unroll
    for (int nt = 0; nt < 4; ++nt) {
      bf16x8 vf = *(const bf16x8*)&Vtc[(nt*16 + l15)*LP + quad*8];
      #pragma unroll
      for (int wq = 0; wq < 2; ++wq)
        o[wq][nt] = __builtin_amdgcn_mfma_f32_16x16x32_bf16(vf, pb0[wq], o[wq][nt], 0, 0, 0);
    }
    #pragma unroll
    for (int wq = 0; wq < 2; ++wq)
      osum[wq] = __builtin_amdgcn_mfma_f32_16x16x32_bf16(ones, pb0[wq], osum[wq], 0, 0, 0);
    __builtin_amdgcn_s_setprio(0);

    // ---- kbh = 1: exp/pack nt 2..3, then PV ----
    bf16x8 pb1[2];
    #pragma unroll
    for (int wq = 0; wq < 2; ++wq)
      #pragma unroll
      for (int nt = 2; nt < 4; ++nt)
        #pragma unroll
        for (int r = 0; r < 4; ++r)
          pb1[wq][(nt & 1)*4 + r] = (bf16)__builtin_amdgcn_exp2f(st[wq][nt][r]);

    __builtin_amdgcn_s_setprio(1);
    #pragma unroll
    for (int nt = 0; nt < 4; ++nt) {
      bf16x8 vf = *(const bf16x8*)&Vtc[(nt*16 + l15)*LP + 32 + quad*8];
      #pragma unroll
      for (int wq = 0; wq < 2; ++wq)
        o[wq][nt] = __builtin_amdgcn_mfma_f32_16x16x32_bf16(vf, pb1[wq], o[wq][nt], 0, 0, 0);
    }
    #pragma unroll
    for (int wq = 0; wq < 2; ++wq)
      osum[wq] = __builtin_amdgcn_mfma_f32_16x16x32_bf16(ones, pb1[wq], osum[wq], 0, 0, 0);
    __builtin_amdgcn_s_setprio(0);

    if (it < 31) {
      const int nxt = cur ^ 1;
      bf16* Ktn = Ktg + nxt*(64*LP);
      bf16* Vtn = Vtg + nxt*(64*LP);
      *(bf16x8*)&Ktn[r0s*LP + cs]     = ka0;
      *(bf16x8*)&Ktn[r0s*LP + cs + 8] = ka1;
      bf16x8 vv;
      vv[0]=va[0]; vv[1]=va[1]; vv[2]=va[2]; vv[3]=va[3];
      vv[4]=vb[0]; vv[5]=vb[1]; vv[6]=vb[2]; vv[7]=vb[3];
      *(bf16x8*)&Vtn[r0s*LP + cs] = vv;
      vv[0]=va[4]; vv[1]=va[5]; vv[2]=va[6]; vv[3]=va[7];
      vv[4]=vb[4]; vv[5]=vb[5]; vv[6]=vb[6]; vv[7]=vb[7];
      *(bf16x8*)&Vtn[r0s*LP + cs + 8] = vv;
      __syncthreads();
    }
  }

  // ---- combine the two k-groups, then normalize + write (group 0) ----
  __syncthreads();                       // all LDS tile reads done
  float* stash = (float*)smem;           // 4 waves x 64 lanes x 36 floats
  const int sidx = (wl*64 + lane) * 36;  // 144 B/lane, 16B-aligned
  if (g == 1) {
    #pragma unroll
    for (int wq = 0; wq < 2; ++wq)
      #pragma unroll
      for (int nt = 0; nt < 4; ++nt)
        *(f32x4*)&stash[sidx + (wq*4 + nt)*4] = o[wq][nt];
    stash[sidx + 32] = osum[0][0];
    stash[sidx + 33] = osum[1][0];
  }
  __syncthreads();
  if (g == 0) {
    #pragma unroll
    for (int wq = 0; wq < 2; ++wq)
      #pragma unroll
      for (int nt = 0; nt < 4; ++nt) {
        f32x4 p = *(const f32x4*)&stash[sidx + (wq*4 + nt)*4];
        #pragma unroll
        for (int r = 0; r < 4; ++r) o[wq][nt][r] += p[r];
      }
    const float s0 = osum[0][0] + stash[sidx + 32];
    const float s1 = osum[1][0] + stash[sidx + 33];

    const int b = bh >> 3, h = bh & 7;
    #pragma unroll
    for (int wq = 0; wq < 2; ++wq) {
      const float inv = 1.f / (wq == 0 ? s0 : s1);
      const size_t row = (size_t)(b*SS + q0 + wl*32 + wq*16 + l15) * CC + h*DD;
      #pragma unroll
      for (int nt = 0; nt < 4; ++nt) {
        bf16x4 ov;
        #pragma unroll
        for (int r = 0; r < 4; ++r) ov[r] = (bf16)(o[wq][nt][r] * inv);
        *(bf16x4*)&aout[row + nt*16 + quad*4] = ov;
      }
    }
  }
}

// ---------------------------------------------------------------------------
// Kernel 3: out = attn @ Wo^T + bo — VERBATIM R10 green (m-pair) source.
// ---------------------------------------------------------------------------
__global__ __launch_bounds__(256) void out_gemm(
    const bf16* __restrict__ A, const bf16* __restrict__ Wob,
    const float* __restrict__ bo, float* __restrict__ out)
{
  __shared__ bf16 Aa[64*LP];
  __shared__ bf16 Ab[64*LP];
  __shared__ bf16 Bt[64*LP];
  const int m0 = blockIdx.x * 128;         // pair: m0 and m0+64
  const int n0 = blockIdx.y * 64;

  const int t = threadIdx.x;
  const int w = t >> 6;
  const int lane = t & 63;
  const int l15 = lane & 15;
  const int quad = lane >> 4;
  const int srow = t >> 2;
  const int scol = (t & 3) << 4;

  f32x4 aca[4], acb[4];
  #pragma unroll
  for (int i = 0; i < 4; ++i)
    #pragma unroll
    for (int j = 0; j < 4; ++j) { aca[i][j] = 0.f; acb[i][j] = 0.f; }

  for (int k0 = 0; k0 < CC; k0 += 64) {
    __syncthreads();
    {
      const bf16* sa = A + (size_t)(m0 + srow) * CC + k0 + scol;
      *(bf16x8*)&Aa[srow*LP + scol]     = ((const bf16x8*)sa)[0];
      *(bf16x8*)&Aa[srow*LP + scol + 8] = ((const bf16x8*)sa)[1];
      const bf16* sb = A + (size_t)(m0 + 64 + srow) * CC + k0 + scol;
      *(bf16x8*)&Ab[srow*LP + scol]     = ((const bf16x8*)sb)[0];
      *(bf16x8*)&Ab[srow*LP + scol + 8] = ((const bf16x8*)sb)[1];
      const bf16* s1 = Wob + (size_t)(n0 + srow) * CC + k0 + scol;
      *(bf16x8*)&Bt[srow*LP + scol]     = ((const bf16x8*)s1)[0];
      *(bf16x8*)&Bt[srow*LP + scol + 8] = ((const bf16x8*)s1)[1];
    }
    __syncthreads();
    #pragma unroll
    for (int c = 0; c < 2; ++c) {
      bf16x8 afa = *(const bf16x8*)&Aa[(w*16 + l15)*LP + c*32 + quad*8];
      bf16x8 afb = *(const bf16x8*)&Ab[(w*16 + l15)*LP + c*32 + quad*8];
      #pragma unroll
      for (int nt = 0; nt < 4; ++nt) {
        bf16x8 bfr = *(const bf16x8*)&Bt[(nt*16 + l15)*LP + c*32 + quad*8];
        aca[nt] = __builtin_amdgcn_mfma_f32_16x16x32_bf16(afa, bfr, aca[nt], 0, 0, 0);
        acb[nt] = __builtin_amdgcn_mfma_f32_16x16x32_bf16(afb, bfr, acb[nt], 0, 0, 0);
      }
    }
  }

  #pragma unroll
  for (int nt = 0; nt < 4; ++nt) {
    const int ng = n0 + nt*16 + l15;
    const float bias = bo[ng];
    #pragma unroll
    for (int r = 0; r < 4; ++r) {
      const int mga = m0 + w*16 + quad*4 + r;
      out[(size_t)mga*CC + ng] = aca[nt][r] + bias;
      const int mgb = m0 + 64 + w*16 + quad*4 + r;
      out[(size_t)mgb*CC + ng] = acb[nt][r] + bias;
    }
  }
}

extern "C" void kernel_launch(void* const* d_in, const int* in_sizes, int n_in,
                              void* d_out, int out_size, void* d_ws, size_t ws_size,
                              hipStream_t stream) {
  const float* hs = (const float*)d_in[0];
  const float* Wq = (const float*)d_in[1];
  const float* Wk = (const float*)d_in[2];
  const float* Wv = (const float*)d_in[3];
  const float* Wo = (const float*)d_in[4];
  const float* bo = (const float*)d_in[5];
  float* out = (float*)d_out;

  const size_t PE = (size_t)BB*HH*SS*DD;      // 4,194,304 elems (8 MiB bf16)
  bf16* ws   = (bf16*)d_ws;
  bf16* qp   = ws;                 // [B][H][S][D] (scale folded via Wb)
  bf16* kp   = ws + PE;            // [B][H][S][D]
  bf16* vtp  = ws + 2*PE;          // [B][H][D][S]  (transposed)
  bf16* Xb   = ws + 3*PE;          // [MM][CC] bf16 (dead after qkv_gemm)
  bf16* aout = ws + 3*PE;          // [B][S][C]    (overwrites Xb after attn)
  bf16* Wob  = qp;                 // [CC][CC] bf16 (qp dead after attn)
  bf16* Wb   = ws + 4*PE;          // [1536][512] bf16 (ws >= 40.5 MB proven by R7)

  cvt_f32_bf16<<<dim3(2048),      256, 0, stream>>>(hs, Xb);        // X -> bf16
  cvt_w       <<<dim3(384),       256, 0, stream>>>(Wq, Wk, Wv, Wb);
  qkv_gemm<<<dim3(MM/128, 12),    256, 0, stream>>>(Xb, Wb, qp, kp, vtp);
  attn_fa <<<dim3(512),           512, 0, stream>>>(qp, kp, vtp, aout);
  cvt_f32_bf16<<<dim3(128),       256, 0, stream>>>(Wo, Wob);       // Wo -> bf16
  out_gemm<<<dim3(MM/128, CC/64), 256, 0, stream>>>(aout, Wob, bo, out);
}